// Round 4
// baseline (448.888 us; speedup 1.0000x reference)
//
#include <hip/hip_runtime.h>

typedef __bf16 bf16;
typedef bf16 bf16x2 __attribute__((ext_vector_type(2)));
typedef bf16 bf16x8 __attribute__((ext_vector_type(8)));
typedef float f32x4 __attribute__((ext_vector_type(4)));

#define B_ 4
#define T_ 4096
#define H_ 16
#define DK_ 64
#define DV_ 64
#define DMODEL_ 1024
#define M_ (B_ * T_)   // 16384
#define EPS_ 1e-6f

#define BARX()  asm volatile("s_barrier" ::: "memory")
#define LGKM0() asm volatile("s_waitcnt lgkmcnt(0)" ::: "memory")

__device__ __forceinline__ void async_ld16(const void* g, void* l) {
    __builtin_amdgcn_global_load_lds(
        (const __attribute__((address_space(1))) unsigned int*)g,
        (__attribute__((address_space(3))) unsigned int*)l,
        16, 0, 0);
}

// ------------------------------------------- transpose + fp32->bf16 convert
struct TPtrs { const float* s[4]; bf16* d[4]; };

__global__ void transpose4(TPtrs p) {
    __shared__ bf16 t[32][33];
    const float* src = p.s[blockIdx.z];
    bf16*        dst = p.d[blockIdx.z];
    const int tx = threadIdx.x, ty = threadIdx.y;
    const int x  = blockIdx.x * 32 + tx;
    const int y0 = blockIdx.y * 32 + ty;
#pragma unroll
    for (int i = 0; i < 32; i += 8)
        t[ty + i][tx] = (bf16)src[(size_t)(y0 + i) * 1024 + x];
    __syncthreads();
    const int xo = blockIdx.y * 32 + tx;   // k index
    const int yo = blockIdx.x * 32 + ty;   // n index
#pragma unroll
    for (int i = 0; i < 32; i += 8)
        dst[(size_t)(yo + i) * 1024 + xo] = t[tx][ty + i];
}

// ----------------------------------------------- fp32 -> bf16 convert pass
__global__ __launch_bounds__(256) void cvt_kernel(
    const float* __restrict__ src, bf16* __restrict__ dst)
{
    const size_t i = (size_t)blockIdx.x * 256 + threadIdx.x;  // per 8 elems
    const float4* s = (const float4*)src + 2 * i;
    float4 a = s[0];
    float4 b = s[1];
    bf16x8 h;
    h[0] = (bf16)a.x; h[1] = (bf16)a.y; h[2] = (bf16)a.z; h[3] = (bf16)a.w;
    h[4] = (bf16)b.x; h[5] = (bf16)b.y; h[6] = (bf16)b.z; h[7] = (bf16)b.w;
    *(bf16x8*)(dst + 8 * i) = h;
}

// ===================== 256x256 8-phase GEMM (T1+T2+T3+T4+T5) =============
// C[M,N] = f(A[M,K] @ Bt[N,K]^T + bias[N])
// 8 waves (2M x 4N), per-wave 128x64 out, BK=64, dbuf LDS 128 KiB.
// Staging in post-last-read slots (P3/P4/P7/P8), full tile per pair of
// phases, gates vmcnt(8): waits only for loads issued 4-5 phases back,
// keeps a full tile (8 loads) in flight across gates.

// stage one half-tile (128 rows x 64 cols bf16): 2 loads/thread.
__device__ __forceinline__ void stage_half(
    const bf16* __restrict__ G, int base_rc, int K,
    char* lds_op_buf, int t, int h, int w, int lane)
{
    const int r8   = lane >> 3;                       // 0..7
    const int row  = h * 128 + w * 8 + r8;
    const int cole = (((lane & 7) ^ r8) << 3);        // pre-swizzled col
    const bf16* g = G + (size_t)(base_rc + row) * K + t * 64 + cole;
    char* l = lds_op_buf + h * 16384 + w * 1024;      // wave-uniform base
    async_ld16(g, l);
    async_ld16(g + (size_t)64 * K, l + 8192);         // +64 rows
}

template<int G>
__device__ __forceinline__ void read_a4(bf16x8 (&aF)[4][2], const char* ab,
                                        int arow, int fq, int l7) {
#pragma unroll
    for (int i = 0; i < 4; ++i)
#pragma unroll
        for (int ks = 0; ks < 2; ++ks)
            aF[i][ks] = *(const bf16x8*)(ab
                + (arow + (G * 4 + i) * 16) * 128
                + ((((ks << 2) + fq) ^ l7) << 4));
}

template<int JP>
__device__ __forceinline__ void read_b2(bf16x8 (&bF)[4][2], const char* bb,
                                        int brow, int fq, int l7) {
#pragma unroll
    for (int j = 0; j < 2; ++j)
#pragma unroll
        for (int ks = 0; ks < 2; ++ks)
            bF[JP * 2 + j][ks] = *(const bf16x8*)(bb
                + (brow + (JP * 2 + j) * 16) * 128
                + ((((ks << 2) + fq) ^ l7) << 4));
}

template<int G, int JP>
__device__ __forceinline__ void mfma_q(f32x4 (&acc)[8][4],
                                       const bf16x8 (&aF)[4][2],
                                       const bf16x8 (&bF)[4][2]) {
#pragma unroll
    for (int i = 0; i < 4; ++i)
#pragma unroll
        for (int j = 0; j < 2; ++j)
#pragma unroll
            for (int ks = 0; ks < 2; ++ks)
                acc[G * 4 + i][JP * 2 + j] =
                    __builtin_amdgcn_mfma_f32_16x16x32_bf16(
                        aF[i][ks], bF[JP * 2 + j][ks],
                        acc[G * 4 + i][JP * 2 + j], 0, 0, 0);
}

template<int ACT, int F32OUT>
__global__ __launch_bounds__(512, 2) void gemm256_kernel(
    const bf16* __restrict__ A, const bf16* __restrict__ Bt,
    const float* __restrict__ bias, void* __restrict__ Cout,
    int M, int N, int K)
{
    __shared__ f32x4 smem4[8192];          // 128 KiB
    char* smem = (char*)smem4;
    char* Ab0 = smem;                      // A buf0 (even tiles)
    char* Ab1 = smem + 32768;              // A buf1 (odd tiles)
    char* Bb0 = smem + 65536;
    char* Bb1 = smem + 98304;

    const int tid  = threadIdx.x;
    const int w    = tid >> 6, lane = tid & 63;
    const int wrow = w >> 2,  wcol = w & 3;
    const int fr = lane & 15, fq = lane >> 4, l7 = lane & 7;
    const int arow = wrow * 128 + fr;
    const int brow = wcol * 64 + fr;

    // T1 bijective XCD swizzle (nwg=256, divisible by 8)
    const int nwg  = gridDim.x * gridDim.y;
    const int flat = blockIdx.y * gridDim.x + blockIdx.x;
    const int swz  = (flat & 7) * (nwg >> 3) + (flat >> 3);
    const int n0   = (swz % gridDim.x) * 256;
    const int m0   = (swz / gridDim.x) * 256;

    const int KT = K >> 6;                 // 16 K-tiles

    f32x4  acc[8][4] = {};
    bf16x8 aF[4][2], bF[4][2];

    // prologue: stage both full tiles t=0 (buf0) and t=1 (buf1)
    stage_half(Bt, n0, K, Bb0, 0, 0, w, lane);
    stage_half(Bt, n0, K, Bb0, 0, 1, w, lane);
    stage_half(A,  m0, K, Ab0, 0, 0, w, lane);
    stage_half(A,  m0, K, Ab0, 0, 1, w, lane);
    stage_half(Bt, n0, K, Bb1, 1, 0, w, lane);
    stage_half(Bt, n0, K, Bb1, 1, 1, w, lane);
    stage_half(A,  m0, K, Ab1, 1, 0, w, lane);
    stage_half(A,  m0, K, Ab1, 1, 1, w, lane);
    asm volatile("s_waitcnt vmcnt(8)" ::: "memory");   // tile0 landed
    BARX();

    for (int it = 0; it < (KT >> 1); ++it) {
        const int  t0   = it * 2, t1 = t0 + 1;
        const bool more = (it < (KT >> 1) - 1);

        // ---- P1: tile t0 (buf0) Q(0,0)
        read_a4<0>(aF, Ab0, arow, fq, l7);
        read_b2<0>(bF, Bb0, brow, fq, l7);
        asm volatile("s_waitcnt lgkmcnt(8)" ::: "memory");
        BARX(); LGKM0();
        __builtin_amdgcn_s_setprio(1);
        mfma_q<0, 0>(acc, aF, bF);
        __builtin_amdgcn_s_setprio(0);
        BARX();

        // ---- P2: Q(0,1)   (last reads of Bb0)
        read_b2<1>(bF, Bb0, brow, fq, l7);
        BARX(); LGKM0();
        __builtin_amdgcn_s_setprio(1);
        mfma_q<0, 1>(acc, aF, bF);
        __builtin_amdgcn_s_setprio(0);
        BARX();

        // ---- P3: Q(1,0) (last reads of Ab0); stage Bb0 <- tile t0+2
        read_a4<1>(aF, Ab0, arow, fq, l7);
        if (more) {
            stage_half(Bt, n0, K, Bb0, t0 + 2, 0, w, lane);
            stage_half(Bt, n0, K, Bb0, t0 + 2, 1, w, lane);
        }
        BARX(); LGKM0();
        __builtin_amdgcn_s_setprio(1);
        mfma_q<1, 0>(acc, aF, bF);
        __builtin_amdgcn_s_setprio(0);
        BARX();

        // ---- P4: Q(1,1); stage Ab0 <- tile t0+2; gate (t1 must be landed)
        if (more) {
            stage_half(A, m0, K, Ab0, t0 + 2, 0, w, lane);
            stage_half(A, m0, K, Ab0, t0 + 2, 1, w, lane);
            asm volatile("s_waitcnt vmcnt(8)" ::: "memory");
        } else {
            asm volatile("s_waitcnt vmcnt(0)" ::: "memory");  // final t1 drain
        }
        BARX();
        __builtin_amdgcn_s_setprio(1);
        mfma_q<1, 1>(acc, aF, bF);
        __builtin_amdgcn_s_setprio(0);
        BARX();

        // ---- P5: tile t1 (buf1) Q(0,0)
        read_a4<0>(aF, Ab1, arow, fq, l7);
        read_b2<0>(bF, Bb1, brow, fq, l7);
        asm volatile("s_waitcnt lgkmcnt(8)" ::: "memory");
        BARX(); LGKM0();
        __builtin_amdgcn_s_setprio(1);
        mfma_q<0, 0>(acc, aF, bF);
        __builtin_amdgcn_s_setprio(0);
        BARX();

        // ---- P6: Q(0,1)   (last reads of Bb1)
        read_b2<1>(bF, Bb1, brow, fq, l7);
        BARX(); LGKM0();
        __builtin_amdgcn_s_setprio(1);
        mfma_q<0, 1>(acc, aF, bF);
        __builtin_amdgcn_s_setprio(0);
        BARX();

        // ---- P7: Q(1,0) (last reads of Ab1); stage Bb1 <- tile t1+2
        read_a4<1>(aF, Ab1, arow, fq, l7);
        if (more) {
            stage_half(Bt, n0, K, Bb1, t1 + 2, 0, w, lane);
            stage_half(Bt, n0, K, Bb1, t1 + 2, 1, w, lane);
        }
        BARX(); LGKM0();
        __builtin_amdgcn_s_setprio(1);
        mfma_q<1, 0>(acc, aF, bF);
        __builtin_amdgcn_s_setprio(0);
        BARX();

        // ---- P8: Q(1,1); stage Ab1 <- tile t1+2; gate (t0+2 for next P1)
        if (more) {
            stage_half(A, m0, K, Ab1, t1 + 2, 0, w, lane);
            stage_half(A, m0, K, Ab1, t1 + 2, 1, w, lane);
            asm volatile("s_waitcnt vmcnt(8)" ::: "memory");
        }
        BARX();
        __builtin_amdgcn_s_setprio(1);
        mfma_q<1, 1>(acc, aF, bF);
        __builtin_amdgcn_s_setprio(0);
        BARX();
    }

    // ---- epilogue: D[row=(lane>>4)*4+r][col=lane&15] per 16x16 tile
    const size_t Ns = (size_t)N;
#pragma unroll
    for (int g = 0; g < 8; ++g) {
#pragma unroll
        for (int j = 0; j < 4; ++j) {
            const int col = n0 + wcol * 64 + j * 16 + fr;
            const float bb = bias[col];
            const int row0 = m0 + wrow * 128 + g * 16 + fq * 4;
#pragma unroll
            for (int r = 0; r < 4; ++r) {
                float x = acc[g][j][r] + bb;
                if (ACT) x = (x > 0.0f) ? (x + 1.0f) : __expf(x);
                if (F32OUT)
                    ((float*)Cout)[(size_t)(row0 + r) * Ns + col] = x;
                else
                    ((bf16*)Cout)[(size_t)(row0 + r) * Ns + col] = (bf16)x;
            }
        }
    }
}

// -------------------------------------------------- kv partial accumulation
__global__ __launch_bounds__(256) void kv_partial_kernel(
    const bf16* __restrict__ Kb, const bf16* __restrict__ V,
    float* __restrict__ kv_part, float* __restrict__ ksum_part)
{
    const int bh = blockIdx.y;
    const int b  = bh >> 4;
    const int h  = bh & 15;
    const int tc = blockIdx.x;
    const int TC = T_ / 8;           // 512
    const int t0 = tc * TC;

    __shared__ float kb[8][64];
    __shared__ float vb[8][64];

    const int tid = threadIdx.x;
    const int dvq = tid >> 4;
    const int dkq = tid & 15;
    const int lr  = tid >> 5;
    const int lc  = (tid & 31) << 1;

    float acc[4][4] = {};
    float ksacc = 0.0f;

    for (int tt0 = 0; tt0 < TC; tt0 += 8) {
        const size_t base = ((size_t)(b * T_) + t0 + tt0 + lr) * 1024 + h * 64 + lc;
        bf16x2 k2 = *(const bf16x2*)&Kb[base];
        bf16x2 v2 = *(const bf16x2*)&V[base];
        kb[lr][lc] = (float)k2[0]; kb[lr][lc + 1] = (float)k2[1];
        vb[lr][lc] = (float)v2[0]; vb[lr][lc + 1] = (float)v2[1];
        __syncthreads();
#pragma unroll
        for (int tt = 0; tt < 8; ++tt) {
            float4 vv = *(const float4*)&vb[tt][dvq * 4];
            float4 kk = *(const float4*)&kb[tt][dkq * 4];
            float va[4] = {vv.x, vv.y, vv.z, vv.w};
            float ka[4] = {kk.x, kk.y, kk.z, kk.w};
#pragma unroll
            for (int i = 0; i < 4; ++i)
#pragma unroll
                for (int j = 0; j < 4; ++j)
                    acc[i][j] += va[i] * ka[j];
        }
        if (tid < 64) {
#pragma unroll
            for (int tt = 0; tt < 8; ++tt) ksacc += kb[tt][tid];
        }
        __syncthreads();
    }

    float* kvp = kv_part + ((size_t)tc * 64 + bh) * 4096;
#pragma unroll
    for (int i = 0; i < 4; ++i) {
        float4 wv = make_float4(acc[i][0], acc[i][1], acc[i][2], acc[i][3]);
        *(float4*)&kvp[(dvq * 4 + i) * 64 + dkq * 4] = wv;
    }
    if (tid < 64)
        ksum_part[((size_t)tc * 64 + bh) * 64 + tid] = ksacc;
}

// ------------------------------------------------------------- kv reduction
__global__ __launch_bounds__(256) void kv_reduce_kernel(
    const float* __restrict__ kv_part, const float* __restrict__ ksum_part,
    bf16* __restrict__ kvb, float* __restrict__ ksum)
{
    const int bh = blockIdx.x;
    const int tid = threadIdx.x;
    for (int e = tid; e < 4096; e += 256) {
        float s = 0.0f;
#pragma unroll
        for (int tc = 0; tc < 8; ++tc)
            s += kv_part[((size_t)tc * 64 + bh) * 4096 + e];
        kvb[(size_t)bh * 4096 + e] = (bf16)s;
    }
    if (tid < 64) {
        float s = 0.0f;
#pragma unroll
        for (int tc = 0; tc < 8; ++tc)
            s += ksum_part[((size_t)tc * 64 + bh) * 64 + tid];
        ksum[bh * 64 + tid] = s;
    }
}

// ------------------------------------------------------------------ attn
__global__ __launch_bounds__(256) void attn_kernel(
    const bf16* __restrict__ Q, const bf16* __restrict__ kvb,
    const float* __restrict__ ksum, bf16* __restrict__ attn)
{
    const int bh = blockIdx.y;
    const int b  = bh >> 4;
    const int h  = bh & 15;
    const int t0 = blockIdx.x * 128;

    __shared__ bf16 As[128 * 64];
    __shared__ bf16 Bs[64 * 64];
    __shared__ float ksum_s[64];
    __shared__ float norm_s[128];

    const int tid  = threadIdx.x;
    const int wave = tid >> 6;
    const int lane = tid & 63;

    const bf16* Qbase = Q + ((size_t)(b * T_) + t0) * 1024 + h * 64;

#pragma unroll
    for (int r2 = 0; r2 < 4; ++r2) {
        const int c   = r2 * 256 + wave * 64 + lane;
        const int row = c >> 3;
        const int ko  = (c & 7) * 8;
        char* l = (char*)As + (size_t)(r2 * 256 + wave * 64) * 16;
        async_ld16(Qbase + (size_t)row * 1024 + ko, l);
    }
    {
        const float4* src = (const float4*)(kvb + (size_t)bh * 4096);
        float4* dst = (float4*)Bs;
        for (int e = tid; e < 512; e += 256) dst[e] = src[e];
    }
    if (tid < 64) ksum_s[tid] = ksum[bh * 64 + tid];
    __syncthreads();

    // norm from the LDS copy of Q (saves a 32MB global re-read);
    // rotated slot order breaks the 128B-row-stride bank pattern.
    if (tid < 128) {
        float s = 0.0f;
#pragma unroll
        for (int u = 0; u < 8; ++u) {
            const int slot = (u + tid) & 7;
            bf16x8 v = *(const bf16x8*)&As[tid * 64 + slot * 8];
#pragma unroll
            for (int e = 0; e < 8; ++e) s += (float)v[e] * ksum_s[slot * 8 + e];
        }
        norm_s[tid] = 1.0f / (s + EPS_);
    }
    __syncthreads();

    const int fr  = lane & 15;
    const int fkq = lane >> 4;
    f32x4 acc[2][4] = {};
#pragma unroll
    for (int ks = 0; ks < 2; ++ks) {
        bf16x8 af[2], bfr[4];
#pragma unroll
        for (int i = 0; i < 2; ++i)
            af[i] = *(const bf16x8*)&As[(wave * 32 + i * 16 + fr) * 64 + ks * 32 + fkq * 8];
#pragma unroll
        for (int j = 0; j < 4; ++j)
            bfr[j] = *(const bf16x8*)&Bs[(j * 16 + fr) * 64 + ks * 32 + fkq * 8];
#pragma unroll
        for (int i = 0; i < 2; ++i)
#pragma unroll
            for (int j = 0; j < 4; ++j)
                acc[i][j] = __builtin_amdgcn_mfma_f32_16x16x32_bf16(
                    af[i], bfr[j], acc[i][j], 0, 0, 0);
    }

    bf16* out = attn + ((size_t)(b * T_) + t0) * 1024 + h * 64;
#pragma unroll
    for (int i = 0; i < 2; ++i)
#pragma unroll
        for (int j = 0; j < 4; ++j)
#pragma unroll
            for (int r = 0; r < 4; ++r) {
                const int row = wave * 32 + i * 16 + fkq * 4 + r;
                const int col = j * 16 + fr;
                out[(size_t)row * 1024 + col] = (bf16)(acc[i][j][r] * norm_s[row]);
            }
}

// ---------------------------------------------------------------- launcher
extern "C" void kernel_launch(void* const* d_in, const int* in_sizes, int n_in,
                              void* d_out, int out_size, void* d_ws, size_t ws_size,
                              hipStream_t stream) {
    const float* query = (const float*)d_in[0];
    const float* key_  = (const float*)d_in[1];
    const float* value = (const float*)d_in[2];
    const float* Wq = (const float*)d_in[3];
    const float* bq = (const float*)d_in[4];
    const float* Wk = (const float*)d_in[5];
    const float* bk = (const float*)d_in[6];
    const float* Wv = (const float*)d_in[7];
    const float* bv = (const float*)d_in[8];
    const float* Wo = (const float*)d_in[9];
    const float* bo = (const float*)d_in[10];

    char* ws = (char*)d_ws;
    char* out8 = (char*)d_out;
    const size_t MB = 1024 * 1024;
    bf16* WqT = (bf16*)(ws + 0 * MB);
    bf16* WkT = (bf16*)(ws + 2 * MB);
    bf16* WvT = (bf16*)(ws + 4 * MB);
    bf16* WoT = (bf16*)(ws + 6 * MB);
    bf16* CVT = (bf16*)(ws + 8 * MB);                    // 32 MiB, reused 3x
    float* kv_part   = (float*)(ws + 40 * MB);           // 8 MiB
    float* ksum_part = (float*)(ws + 48 * MB);           // 128 KiB
    bf16*  kvb  = (bf16*)(ws + 48 * MB + 128 * 1024);    // 512 KiB
    float* ksum = (float*)(ws + 48 * MB + 640 * 1024);   // 16 KiB

    bf16* KB   = (bf16*)out8;                            // d_out [0,32)
    bf16* VB   = (bf16*)(out8 + 32 * MB);                // d_out [32,64)
    bf16* Qb   = (bf16*)out8;                            // reused after kv
    bf16* ATTN = CVT;                                    // reuses CVT slot

    TPtrs tp;
    tp.s[0] = Wq;  tp.s[1] = Wk;  tp.s[2] = Wv;  tp.s[3] = Wo;
    tp.d[0] = WqT; tp.d[1] = WkT; tp.d[2] = WvT; tp.d[3] = WoT;
    transpose4<<<dim3(32, 32, 4), dim3(32, 8, 1), 0, stream>>>(tp);

    const int CVT_BLOCKS = M_ * 1024 / 8 / 256;          // 8192
    const dim3 G256(4, 64);                              // N/256 x M/256

    cvt_kernel<<<CVT_BLOCKS, 256, 0, stream>>>(key_, CVT);
    gemm256_kernel<1, 0><<<G256, 512, 0, stream>>>(CVT, WkT, bk, KB, M_, 1024, 1024);

    cvt_kernel<<<CVT_BLOCKS, 256, 0, stream>>>(value, CVT);
    gemm256_kernel<0, 0><<<G256, 512, 0, stream>>>(CVT, WvT, bv, VB, M_, 1024, 1024);

    kv_partial_kernel<<<dim3(8, 64), 256, 0, stream>>>(KB, VB, kv_part, ksum_part);
    kv_reduce_kernel<<<dim3(64), 256, 0, stream>>>(kv_part, ksum_part, kvb, ksum);

    cvt_kernel<<<CVT_BLOCKS, 256, 0, stream>>>(query, CVT);
    gemm256_kernel<1, 0><<<G256, 512, 0, stream>>>(CVT, WqT, bq, Qb, M_, 1024, 1024);

    attn_kernel<<<dim3(32, 64), 256, 0, stream>>>(Qb, kvb, ksum, ATTN);

    gemm256_kernel<0, 1><<<G256, 512, 0, stream>>>(ATTN, WoT, bo, (float*)d_out, M_, 1024, 1024);
}

// Round 5
// 425.227 us; speedup vs baseline: 1.0556x; 1.0556x over previous
//
#include <hip/hip_runtime.h>

typedef __bf16 bf16;
typedef bf16 bf16x2 __attribute__((ext_vector_type(2)));
typedef bf16 bf16x8 __attribute__((ext_vector_type(8)));
typedef float f32x4 __attribute__((ext_vector_type(4)));

#define B_ 4
#define T_ 4096
#define H_ 16
#define DK_ 64
#define DV_ 64
#define DMODEL_ 1024
#define M_ (B_ * T_)   // 16384
#define EPS_ 1e-6f

#define BARX()  asm volatile("s_barrier" ::: "memory")
#define LGKM0() asm volatile("s_waitcnt lgkmcnt(0)" ::: "memory")

__device__ __forceinline__ void async_ld16(const void* g, void* l) {
    __builtin_amdgcn_global_load_lds(
        (const __attribute__((address_space(1))) unsigned int*)g,
        (__attribute__((address_space(3))) unsigned int*)l,
        16, 0, 0);
}

// ------------------------------------------- transpose + fp32->bf16 convert
struct TPtrs { const float* s[4]; bf16* d[4]; };

__global__ void transpose4(TPtrs p) {
    __shared__ bf16 t[32][33];
    const float* src = p.s[blockIdx.z];
    bf16*        dst = p.d[blockIdx.z];
    const int tx = threadIdx.x, ty = threadIdx.y;
    const int x  = blockIdx.x * 32 + tx;
    const int y0 = blockIdx.y * 32 + ty;
#pragma unroll
    for (int i = 0; i < 32; i += 8)
        t[ty + i][tx] = (bf16)src[(size_t)(y0 + i) * 1024 + x];
    __syncthreads();
    const int xo = blockIdx.y * 32 + tx;   // k index
    const int yo = blockIdx.x * 32 + ty;   // n index
#pragma unroll
    for (int i = 0; i < 32; i += 8)
        dst[(size_t)(yo + i) * 1024 + xo] = t[tx][ty + i];
}

// ----------------------------------------------- fp32 -> bf16 convert pass
__global__ __launch_bounds__(256) void cvt_kernel(
    const float* __restrict__ src, bf16* __restrict__ dst)
{
    const size_t i = (size_t)blockIdx.x * 256 + threadIdx.x;  // per 8 elems
    const float4* s = (const float4*)src + 2 * i;
    float4 a = s[0];
    float4 b = s[1];
    bf16x8 h;
    h[0] = (bf16)a.x; h[1] = (bf16)a.y; h[2] = (bf16)a.z; h[3] = (bf16)a.w;
    h[4] = (bf16)b.x; h[5] = (bf16)b.y; h[6] = (bf16)b.z; h[7] = (bf16)b.w;
    *(bf16x8*)(dst + 8 * i) = h;
}

// ===================== 256x256 8-phase GEMM (T1+T2+T3+T4+T5) =============
// C = f(A[M,K] @ Bt[N,K]^T + bias[N])
// OUTMODE: 0 = bf16 [M,N], 1 = f32 [M,N], 2 = bf16 TRANSPOSED [N,M]
// (mode 2 routes acc through the freed 128KiB LDS, then writes t-contiguous
//  128B chunks -> feeds the MFMA kv kernel which needs [d][t] layout).

// stage one half-tile (128 rows x 64 cols bf16): 2 loads/thread.
__device__ __forceinline__ void stage_half(
    const bf16* __restrict__ G, int base_rc, int K,
    char* lds_op_buf, int t, int h, int w, int lane)
{
    const int r8   = lane >> 3;                       // 0..7
    const int row  = h * 128 + w * 8 + r8;
    const int cole = (((lane & 7) ^ r8) << 3);        // pre-swizzled col
    const bf16* g = G + (size_t)(base_rc + row) * K + t * 64 + cole;
    char* l = lds_op_buf + h * 16384 + w * 1024;      // wave-uniform base
    async_ld16(g, l);
    async_ld16(g + (size_t)64 * K, l + 8192);         // +64 rows
}

template<int G>
__device__ __forceinline__ void read_a4(bf16x8 (&aF)[4][2], const char* ab,
                                        int arow, int fq, int l7) {
#pragma unroll
    for (int i = 0; i < 4; ++i)
#pragma unroll
        for (int ks = 0; ks < 2; ++ks)
            aF[i][ks] = *(const bf16x8*)(ab
                + (arow + (G * 4 + i) * 16) * 128
                + ((((ks << 2) + fq) ^ l7) << 4));
}

template<int JP>
__device__ __forceinline__ void read_b2(bf16x8 (&bF)[4][2], const char* bb,
                                        int brow, int fq, int l7) {
#pragma unroll
    for (int j = 0; j < 2; ++j)
#pragma unroll
        for (int ks = 0; ks < 2; ++ks)
            bF[JP * 2 + j][ks] = *(const bf16x8*)(bb
                + (brow + (JP * 2 + j) * 16) * 128
                + ((((ks << 2) + fq) ^ l7) << 4));
}

template<int G, int JP>
__device__ __forceinline__ void mfma_q(f32x4 (&acc)[8][4],
                                       const bf16x8 (&aF)[4][2],
                                       const bf16x8 (&bF)[4][2]) {
#pragma unroll
    for (int i = 0; i < 4; ++i)
#pragma unroll
        for (int j = 0; j < 2; ++j)
#pragma unroll
            for (int ks = 0; ks < 2; ++ks)
                acc[G * 4 + i][JP * 2 + j] =
                    __builtin_amdgcn_mfma_f32_16x16x32_bf16(
                        aF[i][ks], bF[JP * 2 + j][ks],
                        acc[G * 4 + i][JP * 2 + j], 0, 0, 0);
}

template<int ACT, int OUTMODE>
__global__ __launch_bounds__(512, 2) void gemm256_kernel(
    const bf16* __restrict__ A, const bf16* __restrict__ Bt,
    const float* __restrict__ bias, void* __restrict__ Cout,
    int M, int N, int K)
{
    __shared__ f32x4 smem4[8192];          // 128 KiB
    char* smem = (char*)smem4;
    char* Ab0 = smem;                      // A buf0 (even tiles)
    char* Ab1 = smem + 32768;              // A buf1 (odd tiles)
    char* Bb0 = smem + 65536;
    char* Bb1 = smem + 98304;

    const int tid  = threadIdx.x;
    const int w    = tid >> 6, lane = tid & 63;
    const int wrow = w >> 2,  wcol = w & 3;
    const int fr = lane & 15, fq = lane >> 4, l7 = lane & 7;
    const int arow = wrow * 128 + fr;
    const int brow = wcol * 64 + fr;

    // T1 bijective XCD swizzle (nwg=256, divisible by 8)
    const int nwg  = gridDim.x * gridDim.y;
    const int flat = blockIdx.y * gridDim.x + blockIdx.x;
    const int swz  = (flat & 7) * (nwg >> 3) + (flat >> 3);
    const int n0   = (swz % gridDim.x) * 256;
    const int m0   = (swz / gridDim.x) * 256;

    const int KT = K >> 6;                 // 16 K-tiles

    f32x4  acc[8][4] = {};
    bf16x8 aF[4][2], bF[4][2];

    // prologue: stage both full tiles t=0 (buf0) and t=1 (buf1)
    stage_half(Bt, n0, K, Bb0, 0, 0, w, lane);
    stage_half(Bt, n0, K, Bb0, 0, 1, w, lane);
    stage_half(A,  m0, K, Ab0, 0, 0, w, lane);
    stage_half(A,  m0, K, Ab0, 0, 1, w, lane);
    stage_half(Bt, n0, K, Bb1, 1, 0, w, lane);
    stage_half(Bt, n0, K, Bb1, 1, 1, w, lane);
    stage_half(A,  m0, K, Ab1, 1, 0, w, lane);
    stage_half(A,  m0, K, Ab1, 1, 1, w, lane);
    asm volatile("s_waitcnt vmcnt(8)" ::: "memory");   // tile0 landed
    BARX();

    for (int it = 0; it < (KT >> 1); ++it) {
        const int  t0   = it * 2, t1 = t0 + 1;
        const bool more = (it < (KT >> 1) - 1);

        // ---- P1: tile t0 (buf0) Q(0,0)
        read_a4<0>(aF, Ab0, arow, fq, l7);
        read_b2<0>(bF, Bb0, brow, fq, l7);
        asm volatile("s_waitcnt lgkmcnt(8)" ::: "memory");
        BARX(); LGKM0();
        __builtin_amdgcn_s_setprio(1);
        mfma_q<0, 0>(acc, aF, bF);
        __builtin_amdgcn_s_setprio(0);
        BARX();

        // ---- P2: Q(0,1)   (last reads of Bb0)
        read_b2<1>(bF, Bb0, brow, fq, l7);
        BARX(); LGKM0();
        __builtin_amdgcn_s_setprio(1);
        mfma_q<0, 1>(acc, aF, bF);
        __builtin_amdgcn_s_setprio(0);
        BARX();

        // ---- P3: Q(1,0) (last reads of Ab0); stage Bb0 <- tile t0+2
        read_a4<1>(aF, Ab0, arow, fq, l7);
        if (more) {
            stage_half(Bt, n0, K, Bb0, t0 + 2, 0, w, lane);
            stage_half(Bt, n0, K, Bb0, t0 + 2, 1, w, lane);
        }
        BARX(); LGKM0();
        __builtin_amdgcn_s_setprio(1);
        mfma_q<1, 0>(acc, aF, bF);
        __builtin_amdgcn_s_setprio(0);
        BARX();

        // ---- P4: Q(1,1); stage Ab0 <- tile t0+2; gate (t1 must be landed)
        if (more) {
            stage_half(A, m0, K, Ab0, t0 + 2, 0, w, lane);
            stage_half(A, m0, K, Ab0, t0 + 2, 1, w, lane);
            asm volatile("s_waitcnt vmcnt(8)" ::: "memory");
        } else {
            asm volatile("s_waitcnt vmcnt(0)" ::: "memory");  // final t1 drain
        }
        BARX();
        __builtin_amdgcn_s_setprio(1);
        mfma_q<1, 1>(acc, aF, bF);
        __builtin_amdgcn_s_setprio(0);
        BARX();

        // ---- P5: tile t1 (buf1) Q(0,0)
        read_a4<0>(aF, Ab1, arow, fq, l7);
        read_b2<0>(bF, Bb1, brow, fq, l7);
        asm volatile("s_waitcnt lgkmcnt(8)" ::: "memory");
        BARX(); LGKM0();
        __builtin_amdgcn_s_setprio(1);
        mfma_q<0, 0>(acc, aF, bF);
        __builtin_amdgcn_s_setprio(0);
        BARX();

        // ---- P6: Q(0,1)   (last reads of Bb1)
        read_b2<1>(bF, Bb1, brow, fq, l7);
        BARX(); LGKM0();
        __builtin_amdgcn_s_setprio(1);
        mfma_q<0, 1>(acc, aF, bF);
        __builtin_amdgcn_s_setprio(0);
        BARX();

        // ---- P7: Q(1,0) (last reads of Ab1); stage Bb1 <- tile t1+2
        read_a4<1>(aF, Ab1, arow, fq, l7);
        if (more) {
            stage_half(Bt, n0, K, Bb1, t1 + 2, 0, w, lane);
            stage_half(Bt, n0, K, Bb1, t1 + 2, 1, w, lane);
        }
        BARX(); LGKM0();
        __builtin_amdgcn_s_setprio(1);
        mfma_q<1, 0>(acc, aF, bF);
        __builtin_amdgcn_s_setprio(0);
        BARX();

        // ---- P8: Q(1,1); stage Ab1 <- tile t1+2; gate (t0+2 for next P1)
        if (more) {
            stage_half(A, m0, K, Ab1, t1 + 2, 0, w, lane);
            stage_half(A, m0, K, Ab1, t1 + 2, 1, w, lane);
            asm volatile("s_waitcnt vmcnt(8)" ::: "memory");
        }
        BARX();
        __builtin_amdgcn_s_setprio(1);
        mfma_q<1, 1>(acc, aF, bF);
        __builtin_amdgcn_s_setprio(0);
        BARX();
    }

    const size_t Ns = (size_t)N;
    if constexpr (OUTMODE == 2) {
        // transposed epilogue: acc -> LDS bf16 [256][256] (XOR-swizzled
        // 16B blocks keyed by row&7) -> coalesced [N,M] global writes.
        __syncthreads();
        char* eb = smem;
#pragma unroll
        for (int g = 0; g < 8; ++g)
#pragma unroll
            for (int j = 0; j < 4; ++j) {
                const int col = wcol * 64 + j * 16 + fr;
                const float bb = bias[n0 + col];
#pragma unroll
                for (int r = 0; r < 4; ++r) {
                    float x = acc[g][j][r] + bb;
                    if (ACT) x = (x > 0.0f) ? (x + 1.0f) : __expf(x);
                    const int row = wrow * 128 + g * 16 + fq * 4 + r;
                    *(bf16*)(eb + row * 512
                        + ((((col >> 3) ^ (row & 7)) << 4) | ((col & 7) << 1)))
                        = (bf16)x;
                }
            }
        __syncthreads();
        bf16* Cp = (bf16*)Cout;
#pragma unroll
        for (int o = 0; o < 16; ++o) {
            const int n = (tid >> 3) + (o & 3) * 64;
            const int m = (tid & 7) * 8 + (o >> 2) * 64;
            bf16x8 v;
#pragma unroll
            for (int e = 0; e < 8; ++e) {
                const int row = m + e;
                v[e] = *(const bf16*)(eb + row * 512
                        + ((((n >> 3) ^ (row & 7)) << 4) | ((n & 7) << 1)));
            }
            *(bf16x8*)(Cp + (size_t)(n0 + n) * M + m0 + m) = v;
        }
    } else {
        // direct epilogue: D[row=(lane>>4)*4+r][col=lane&15] per 16x16 tile
#pragma unroll
        for (int g = 0; g < 8; ++g) {
#pragma unroll
            for (int j = 0; j < 4; ++j) {
                const int col = n0 + wcol * 64 + j * 16 + fr;
                const float bb = bias[col];
                const int row0 = m0 + wrow * 128 + g * 16 + fq * 4;
#pragma unroll
                for (int r = 0; r < 4; ++r) {
                    float x = acc[g][j][r] + bb;
                    if (ACT) x = (x > 0.0f) ? (x + 1.0f) : __expf(x);
                    if (OUTMODE == 1)
                        ((float*)Cout)[(size_t)(row0 + r) * Ns + col] = x;
                    else
                        ((bf16*)Cout)[(size_t)(row0 + r) * Ns + col] = (bf16)x;
                }
            }
        }
    }
}

// ----------------------------- kv partial accumulation (MFMA over KT/VT)
// KT/VT layout [1024 = h*64+d][16384 = b*T+t]; per (bh, t-chunk of 512):
// kv[dv][dk] += sum_t VT[dv][t]*KT[dk][t]  -- a 64x64xK MFMA GEMM.
__global__ __launch_bounds__(256) void kv_partial_kernel(
    const bf16* __restrict__ KT, const bf16* __restrict__ VT,
    float* __restrict__ kv_part, float* __restrict__ ksum_part)
{
    const int bh = blockIdx.y, b = bh >> 4, h = bh & 15;
    const int tc = blockIdx.x;
    __shared__ char lds[32768];            // 2 bufs x (V 8K + K 8K)

    const int tid = threadIdx.x, wv = tid >> 6, lane = tid & 63;
    const int fr = lane & 15, fq = lane >> 4, l7 = lane & 7;

    // staging geometry: tile [64 d-rows][64 t] per matrix; rows r1, r1+32.
    const int r1 = wv * 8 + (lane >> 3);
    const int c1 = ((lane & 7) ^ (r1 & 7)) << 3;      // pre-swizzled t-offset
    const size_t g1 = (size_t)(h * 64 + r1) * M_ + (size_t)b * T_ + c1;
    const size_t g2 = g1 + (size_t)32 * M_;
    const int dstoff = (wv * 64 + lane) * 16;

    f32x4 acc[4] = {};
    float ksa = 0.0f;
    const int rk = tid >> 2, qk = tid & 3;

    {   // prologue: tile 0 into buf0
        const size_t mo = (size_t)tc * 512;
        async_ld16(VT + g1 + mo, lds + dstoff);
        async_ld16(VT + g2 + mo, lds + 4096 + dstoff);
        async_ld16(KT + g1 + mo, lds + 8192 + dstoff);
        async_ld16(KT + g2 + mo, lds + 12288 + dstoff);
    }
    for (int it = 0; it < 8; ++it) {
        char* cur = lds + (it & 1) * 16384;
        char* nxt = lds + ((it & 1) ^ 1) * 16384;
        if (it < 7) {
            const size_t mo = (size_t)tc * 512 + (it + 1) * 64;
            async_ld16(VT + g1 + mo, nxt + dstoff);
            async_ld16(VT + g2 + mo, nxt + 4096 + dstoff);
            async_ld16(KT + g1 + mo, nxt + 8192 + dstoff);
            async_ld16(KT + g2 + mo, nxt + 12288 + dstoff);
            asm volatile("s_waitcnt vmcnt(4)" ::: "memory");
        } else {
            asm volatile("s_waitcnt vmcnt(0)" ::: "memory");
        }
        BARX();
        const char* Vb = cur;
        const char* Kb = cur + 8192;
#pragma unroll
        for (int ks = 0; ks < 2; ++ks) {
            bf16x8 av = *(const bf16x8*)(Vb + (wv * 16 + fr) * 128
                        + ((((ks << 2) + fq) ^ l7) << 4));
#pragma unroll
            for (int j = 0; j < 4; ++j) {
                bf16x8 bk = *(const bf16x8*)(Kb + (j * 16 + fr) * 128
                            + ((((ks << 2) + fq) ^ l7) << 4));
                acc[j] = __builtin_amdgcn_mfma_f32_16x16x32_bf16(
                    av, bk, acc[j], 0, 0, 0);
            }
        }
        {   // ksum partial from the staged K tile
            bf16x8 s0 = *(const bf16x8*)(Kb + rk * 128 + (((2 * qk) ^ (rk & 7)) << 4));
            bf16x8 s1 = *(const bf16x8*)(Kb + rk * 128 + (((2 * qk + 1) ^ (rk & 7)) << 4));
#pragma unroll
            for (int e = 0; e < 8; ++e) ksa += (float)s0[e] + (float)s1[e];
        }
        BARX();
    }

    float* kvp = kv_part + ((size_t)tc * 64 + bh) * 4096;
#pragma unroll
    for (int j = 0; j < 4; ++j)
#pragma unroll
        for (int r = 0; r < 4; ++r)
            kvp[(wv * 16 + fq * 4 + r) * 64 + j * 16 + fr] = acc[j][r];

    float s = ksa;
    s += __shfl_xor(s, 1);
    s += __shfl_xor(s, 2);
    if (qk == 0) ksum_part[((size_t)tc * 64 + bh) * 64 + rk] = s;
}

// ------------------------------------------------------------- kv reduction
__global__ __launch_bounds__(256) void kv_reduce_kernel(
    const float* __restrict__ kv_part, const float* __restrict__ ksum_part,
    bf16* __restrict__ kvb, float* __restrict__ ksum)
{
    const int bh = blockIdx.x;
    const int tid = threadIdx.x;
    for (int e = tid; e < 4096; e += 256) {
        float s = 0.0f;
#pragma unroll
        for (int tc = 0; tc < 8; ++tc)
            s += kv_part[((size_t)tc * 64 + bh) * 4096 + e];
        kvb[(size_t)bh * 4096 + e] = (bf16)s;
    }
    if (tid < 64) {
        float s = 0.0f;
#pragma unroll
        for (int tc = 0; tc < 8; ++tc)
            s += ksum_part[((size_t)tc * 64 + bh) * 64 + tid];
        ksum[bh * 64 + tid] = s;
    }
}

// ------------------------------------------------------------------ attn
__global__ __launch_bounds__(256) void attn_kernel(
    const bf16* __restrict__ Q, const bf16* __restrict__ kvb,
    const float* __restrict__ ksum, bf16* __restrict__ attn)
{
    const int bh = blockIdx.y;
    const int b  = bh >> 4;
    const int h  = bh & 15;
    const int t0 = blockIdx.x * 128;

    __shared__ bf16 As[128 * 64];
    __shared__ bf16 Bs[64 * 64];
    __shared__ float ksum_s[64];
    __shared__ float norm_s[128];

    const int tid  = threadIdx.x;
    const int wave = tid >> 6;
    const int lane = tid & 63;

    const bf16* Qbase = Q + ((size_t)(b * T_) + t0) * 1024 + h * 64;

#pragma unroll
    for (int r2 = 0; r2 < 4; ++r2) {
        const int c   = r2 * 256 + wave * 64 + lane;
        const int row = c >> 3;
        const int ko  = (c & 7) * 8;
        char* l = (char*)As + (size_t)(r2 * 256 + wave * 64) * 16;
        async_ld16(Qbase + (size_t)row * 1024 + ko, l);
    }
    {
        const float4* src = (const float4*)(kvb + (size_t)bh * 4096);
        float4* dst = (float4*)Bs;
        for (int e = tid; e < 512; e += 256) dst[e] = src[e];
    }
    if (tid < 64) ksum_s[tid] = ksum[bh * 64 + tid];
    __syncthreads();

    // norm from the LDS copy of Q (saves a 32MB global re-read);
    // rotated slot order breaks the 128B-row-stride bank pattern.
    if (tid < 128) {
        float s = 0.0f;
#pragma unroll
        for (int u = 0; u < 8; ++u) {
            const int slot = (u + tid) & 7;
            bf16x8 v = *(const bf16x8*)&As[tid * 64 + slot * 8];
#pragma unroll
            for (int e = 0; e < 8; ++e) s += (float)v[e] * ksum_s[slot * 8 + e];
        }
        norm_s[tid] = 1.0f / (s + EPS_);
    }
    __syncthreads();

    const int fr  = lane & 15;
    const int fkq = lane >> 4;
    f32x4 acc[2][4] = {};
#pragma unroll
    for (int ks = 0; ks < 2; ++ks) {
        bf16x8 af[2], bfr[4];
#pragma unroll
        for (int i = 0; i < 2; ++i)
            af[i] = *(const bf16x8*)&As[(wave * 32 + i * 16 + fr) * 64 + ks * 32 + fkq * 8];
#pragma unroll
        for (int j = 0; j < 4; ++j)
            bfr[j] = *(const bf16x8*)&Bs[(j * 16 + fr) * 64 + ks * 32 + fkq * 8];
#pragma unroll
        for (int i = 0; i < 2; ++i)
#pragma unroll
            for (int j = 0; j < 4; ++j)
                acc[i][j] = __builtin_amdgcn_mfma_f32_16x16x32_bf16(
                    af[i], bfr[j], acc[i][j], 0, 0, 0);
    }

    bf16* out = attn + ((size_t)(b * T_) + t0) * 1024 + h * 64;
#pragma unroll
    for (int i = 0; i < 2; ++i)
#pragma unroll
        for (int j = 0; j < 4; ++j)
#pragma unroll
            for (int r = 0; r < 4; ++r) {
                const int row = wave * 32 + i * 16 + fkq * 4 + r;
                const int col = j * 16 + fr;
                out[(size_t)row * 1024 + col] = (bf16)(acc[i][j][r] * norm_s[row]);
            }
}

// ---------------------------------------------------------------- launcher
extern "C" void kernel_launch(void* const* d_in, const int* in_sizes, int n_in,
                              void* d_out, int out_size, void* d_ws, size_t ws_size,
                              hipStream_t stream) {
    const float* query = (const float*)d_in[0];
    const float* key_  = (const float*)d_in[1];
    const float* value = (const float*)d_in[2];
    const float* Wq = (const float*)d_in[3];
    const float* bq = (const float*)d_in[4];
    const float* Wk = (const float*)d_in[5];
    const float* bk = (const float*)d_in[6];
    const float* Wv = (const float*)d_in[7];
    const float* bv = (const float*)d_in[8];
    const float* Wo = (const float*)d_in[9];
    const float* bo = (const float*)d_in[10];

    char* ws = (char*)d_ws;
    char* out8 = (char*)d_out;
    const size_t MB = 1024 * 1024;
    bf16* WqT = (bf16*)(ws + 0 * MB);
    bf16* WkT = (bf16*)(ws + 2 * MB);
    bf16* WvT = (bf16*)(ws + 4 * MB);
    bf16* WoT = (bf16*)(ws + 6 * MB);
    bf16* CVT = (bf16*)(ws + 8 * MB);                    // 32 MiB, reused 3x
    float* kv_part   = (float*)(ws + 40 * MB);           // 8 MiB
    float* ksum_part = (float*)(ws + 48 * MB);           // 128 KiB
    bf16*  kvb  = (bf16*)(ws + 48 * MB + 128 * 1024);    // 512 KiB
    float* ksum = (float*)(ws + 48 * MB + 640 * 1024);   // 16 KiB

    bf16* KTg  = (bf16*)out8;                            // d_out [0,32): K^T
    bf16* VTg  = (bf16*)(out8 + 32 * MB);                // d_out [32,64): V^T
    bf16* Qb   = (bf16*)out8;                            // reused after kv
    bf16* ATTN = CVT;                                    // reuses CVT slot

    TPtrs tp;
    tp.s[0] = Wq;  tp.s[1] = Wk;  tp.s[2] = Wv;  tp.s[3] = Wo;
    tp.d[0] = WqT; tp.d[1] = WkT; tp.d[2] = WvT; tp.d[3] = WoT;
    transpose4<<<dim3(32, 32, 4), dim3(32, 8, 1), 0, stream>>>(tp);

    const int CVT_BLOCKS = M_ * 1024 / 8 / 256;          // 8192
    const dim3 G256(4, 64);                              // N/256 x M/256

    cvt_kernel<<<CVT_BLOCKS, 256, 0, stream>>>(key_, CVT);
    gemm256_kernel<1, 2><<<G256, 512, 0, stream>>>(CVT, WkT, bk, KTg, M_, 1024, 1024);

    cvt_kernel<<<CVT_BLOCKS, 256, 0, stream>>>(value, CVT);
    gemm256_kernel<0, 2><<<G256, 512, 0, stream>>>(CVT, WvT, bv, VTg, M_, 1024, 1024);

    kv_partial_kernel<<<dim3(8, 64), 256, 0, stream>>>(KTg, VTg, kv_part, ksum_part);
    kv_reduce_kernel<<<dim3(64), 256, 0, stream>>>(kv_part, ksum_part, kvb, ksum);

    cvt_kernel<<<CVT_BLOCKS, 256, 0, stream>>>(query, CVT);
    gemm256_kernel<1, 0><<<G256, 512, 0, stream>>>(CVT, WqT, bq, Qb, M_, 1024, 1024);

    attn_kernel<<<dim3(32, 64), 256, 0, stream>>>(Qb, kvb, ksum, ATTN);

    gemm256_kernel<0, 1><<<G256, 512, 0, stream>>>(ATTN, WoT, bo, (float*)d_out, M_, 1024, 1024);
}

// Round 6
// 404.551 us; speedup vs baseline: 1.1096x; 1.0511x over previous
//
#include <hip/hip_runtime.h>

typedef __bf16 bf16;
typedef bf16 bf16x2 __attribute__((ext_vector_type(2)));
typedef bf16 bf16x8 __attribute__((ext_vector_type(8)));
typedef float f32x4 __attribute__((ext_vector_type(4)));

#define B_ 4
#define T_ 4096
#define H_ 16
#define DK_ 64
#define DV_ 64
#define DMODEL_ 1024
#define M_ (B_ * T_)   // 16384
#define EPS_ 1e-6f

#define BARX()  asm volatile("s_barrier" ::: "memory")
#define LGKM0() asm volatile("s_waitcnt lgkmcnt(0)" ::: "memory")

__device__ __forceinline__ void async_ld16(const void* g, void* l) {
    __builtin_amdgcn_global_load_lds(
        (const __attribute__((address_space(1))) unsigned int*)g,
        (__attribute__((address_space(3))) unsigned int*)l,
        16, 0, 0);
}

// ------------------------------------------- transpose + fp32->bf16 convert
struct TPtrs { const float* s[4]; bf16* d[4]; };

__global__ void transpose4(TPtrs p) {
    __shared__ bf16 t[32][33];
    const float* src = p.s[blockIdx.z];
    bf16*        dst = p.d[blockIdx.z];
    const int tx = threadIdx.x, ty = threadIdx.y;
    const int x  = blockIdx.x * 32 + tx;
    const int y0 = blockIdx.y * 32 + ty;
#pragma unroll
    for (int i = 0; i < 32; i += 8)
        t[ty + i][tx] = (bf16)src[(size_t)(y0 + i) * 1024 + x];
    __syncthreads();
    const int xo = blockIdx.y * 32 + tx;   // k index
    const int yo = blockIdx.x * 32 + ty;   // n index
#pragma unroll
    for (int i = 0; i < 32; i += 8)
        dst[(size_t)(yo + i) * 1024 + xo] = t[tx][ty + i];
}

// ----------------------------------------------- fp32 -> bf16 convert pass
__global__ __launch_bounds__(256) void cvt_kernel(
    const float* __restrict__ src, bf16* __restrict__ dst)
{
    const size_t i = (size_t)blockIdx.x * 256 + threadIdx.x;  // per 8 elems
    const float4* s = (const float4*)src + 2 * i;
    float4 a = s[0];
    float4 b = s[1];
    bf16x8 h;
    h[0] = (bf16)a.x; h[1] = (bf16)a.y; h[2] = (bf16)a.z; h[3] = (bf16)a.w;
    h[4] = (bf16)b.x; h[5] = (bf16)b.y; h[6] = (bf16)b.z; h[7] = (bf16)b.w;
    *(bf16x8*)(dst + 8 * i) = h;
}

// ===================== 256x256 8-phase GEMM (T1+T2+T3+T4+T5) =============
// C = f(A[M,K] @ Bt[N,K]^T + bias[N])
// OUTMODE: 1 = f32 [M,N]
//          2 = bf16 TRANSPOSED [N,M]  (for the kv MFMA kernel)
//          3 = FUSED ATTN: per-wave head slice, O = phi(q)*kv2 * norm,
//              norm from augmented kv2 rows 64..95 (ksum hi/lo bf16).

// stage one half-tile (128 rows x 64 cols bf16): 2 loads/thread.
__device__ __forceinline__ void stage_half(
    const bf16* __restrict__ G, int base_rc, int K,
    char* lds_op_buf, int t, int h, int w, int lane)
{
    const int r8   = lane >> 3;                       // 0..7
    const int row  = h * 128 + w * 8 + r8;
    const int cole = (((lane & 7) ^ r8) << 3);        // pre-swizzled col
    const bf16* g = G + (size_t)(base_rc + row) * K + t * 64 + cole;
    char* l = lds_op_buf + h * 16384 + w * 1024;      // wave-uniform base
    async_ld16(g, l);
    async_ld16(g + (size_t)64 * K, l + 8192);         // +64 rows
}

template<int G>
__device__ __forceinline__ void read_a4(bf16x8 (&aF)[4][2], const char* ab,
                                        int arow, int fq, int l7) {
#pragma unroll
    for (int i = 0; i < 4; ++i)
#pragma unroll
        for (int ks = 0; ks < 2; ++ks)
            aF[i][ks] = *(const bf16x8*)(ab
                + (arow + (G * 4 + i) * 16) * 128
                + ((((ks << 2) + fq) ^ l7) << 4));
}

template<int JP>
__device__ __forceinline__ void read_b2(bf16x8 (&bF)[4][2], const char* bb,
                                        int brow, int fq, int l7) {
#pragma unroll
    for (int j = 0; j < 2; ++j)
#pragma unroll
        for (int ks = 0; ks < 2; ++ks)
            bF[JP * 2 + j][ks] = *(const bf16x8*)(bb
                + (brow + (JP * 2 + j) * 16) * 128
                + ((((ks << 2) + fq) ^ l7) << 4));
}

template<int G, int JP>
__device__ __forceinline__ void mfma_q(f32x4 (&acc)[8][4],
                                       const bf16x8 (&aF)[4][2],
                                       const bf16x8 (&bF)[4][2]) {
#pragma unroll
    for (int i = 0; i < 4; ++i)
#pragma unroll
        for (int j = 0; j < 2; ++j)
#pragma unroll
            for (int ks = 0; ks < 2; ++ks)
                acc[G * 4 + i][JP * 2 + j] =
                    __builtin_amdgcn_mfma_f32_16x16x32_bf16(
                        aF[i][ks], bF[JP * 2 + j][ks],
                        acc[G * 4 + i][JP * 2 + j], 0, 0, 0);
}

template<int ACT, int OUTMODE>
__global__ __launch_bounds__(512, 2) void gemm256_kernel(
    const bf16* __restrict__ A, const bf16* __restrict__ Bt,
    const float* __restrict__ bias, void* __restrict__ Cout,
    const bf16* __restrict__ KV2,   // OUTMODE==3: augmented kv [96][64]/bh
    int M, int N, int K)
{
    __shared__ f32x4 smem4[8192];          // 128 KiB
    char* smem = (char*)smem4;
    char* Ab0 = smem;                      // A buf0 (even tiles)
    char* Ab1 = smem + 32768;              // A buf1 (odd tiles)
    char* Bb0 = smem + 65536;
    char* Bb1 = smem + 98304;

    const int tid  = threadIdx.x;
    const int w    = tid >> 6, lane = tid & 63;
    const int wrow = w >> 2,  wcol = w & 3;
    const int fr = lane & 15, fq = lane >> 4, l7 = lane & 7;
    const int arow = wrow * 128 + fr;
    const int brow = wcol * 64 + fr;

    // T1 bijective XCD swizzle (nwg=256, divisible by 8)
    const int nwg  = gridDim.x * gridDim.y;
    const int flat = blockIdx.y * gridDim.x + blockIdx.x;
    const int swz  = (flat & 7) * (nwg >> 3) + (flat >> 3);
    const int n0   = (swz % gridDim.x) * 256;
    const int m0   = (swz / gridDim.x) * 256;

    const int KT = K >> 6;                 // 16 K-tiles

    f32x4  acc[8][4] = {};
    bf16x8 aF[4][2], bF[4][2];

    // prologue: stage both full tiles t=0 (buf0) and t=1 (buf1)
    stage_half(Bt, n0, K, Bb0, 0, 0, w, lane);
    stage_half(Bt, n0, K, Bb0, 0, 1, w, lane);
    stage_half(A,  m0, K, Ab0, 0, 0, w, lane);
    stage_half(A,  m0, K, Ab0, 0, 1, w, lane);
    stage_half(Bt, n0, K, Bb1, 1, 0, w, lane);
    stage_half(Bt, n0, K, Bb1, 1, 1, w, lane);
    stage_half(A,  m0, K, Ab1, 1, 0, w, lane);
    stage_half(A,  m0, K, Ab1, 1, 1, w, lane);
    asm volatile("s_waitcnt vmcnt(8)" ::: "memory");   // tile0 landed
    BARX();

    for (int it = 0; it < (KT >> 1); ++it) {
        const int  t0   = it * 2, t1 = t0 + 1;
        const bool more = (it < (KT >> 1) - 1);

        // ---- P1: tile t0 (buf0) Q(0,0)
        read_a4<0>(aF, Ab0, arow, fq, l7);
        read_b2<0>(bF, Bb0, brow, fq, l7);
        asm volatile("s_waitcnt lgkmcnt(8)" ::: "memory");
        BARX(); LGKM0();
        __builtin_amdgcn_s_setprio(1);
        mfma_q<0, 0>(acc, aF, bF);
        __builtin_amdgcn_s_setprio(0);
        BARX();

        // ---- P2: Q(0,1)   (last reads of Bb0)
        read_b2<1>(bF, Bb0, brow, fq, l7);
        BARX(); LGKM0();
        __builtin_amdgcn_s_setprio(1);
        mfma_q<0, 1>(acc, aF, bF);
        __builtin_amdgcn_s_setprio(0);
        BARX();

        // ---- P3: Q(1,0) (last reads of Ab0); stage Bb0 <- tile t0+2
        read_a4<1>(aF, Ab0, arow, fq, l7);
        if (more) {
            stage_half(Bt, n0, K, Bb0, t0 + 2, 0, w, lane);
            stage_half(Bt, n0, K, Bb0, t0 + 2, 1, w, lane);
        }
        BARX(); LGKM0();
        __builtin_amdgcn_s_setprio(1);
        mfma_q<1, 0>(acc, aF, bF);
        __builtin_amdgcn_s_setprio(0);
        BARX();

        // ---- P4: Q(1,1); stage Ab0 <- tile t0+2; gate (t1 must be landed)
        if (more) {
            stage_half(A, m0, K, Ab0, t0 + 2, 0, w, lane);
            stage_half(A, m0, K, Ab0, t0 + 2, 1, w, lane);
            asm volatile("s_waitcnt vmcnt(8)" ::: "memory");
        } else {
            asm volatile("s_waitcnt vmcnt(0)" ::: "memory");  // final t1 drain
        }
        BARX();
        __builtin_amdgcn_s_setprio(1);
        mfma_q<1, 1>(acc, aF, bF);
        __builtin_amdgcn_s_setprio(0);
        BARX();

        // ---- P5: tile t1 (buf1) Q(0,0)
        read_a4<0>(aF, Ab1, arow, fq, l7);
        read_b2<0>(bF, Bb1, brow, fq, l7);
        asm volatile("s_waitcnt lgkmcnt(8)" ::: "memory");
        BARX(); LGKM0();
        __builtin_amdgcn_s_setprio(1);
        mfma_q<0, 0>(acc, aF, bF);
        __builtin_amdgcn_s_setprio(0);
        BARX();

        // ---- P6: Q(0,1)   (last reads of Bb1)
        read_b2<1>(bF, Bb1, brow, fq, l7);
        BARX(); LGKM0();
        __builtin_amdgcn_s_setprio(1);
        mfma_q<0, 1>(acc, aF, bF);
        __builtin_amdgcn_s_setprio(0);
        BARX();

        // ---- P7: Q(1,0) (last reads of Ab1); stage Bb1 <- tile t1+2
        read_a4<1>(aF, Ab1, arow, fq, l7);
        if (more) {
            stage_half(Bt, n0, K, Bb1, t1 + 2, 0, w, lane);
            stage_half(Bt, n0, K, Bb1, t1 + 2, 1, w, lane);
        }
        BARX(); LGKM0();
        __builtin_amdgcn_s_setprio(1);
        mfma_q<1, 0>(acc, aF, bF);
        __builtin_amdgcn_s_setprio(0);
        BARX();

        // ---- P8: Q(1,1); stage Ab1 <- tile t1+2; gate (t0+2 for next P1)
        if (more) {
            stage_half(A, m0, K, Ab1, t1 + 2, 0, w, lane);
            stage_half(A, m0, K, Ab1, t1 + 2, 1, w, lane);
            asm volatile("s_waitcnt vmcnt(8)" ::: "memory");
        }
        BARX();
        __builtin_amdgcn_s_setprio(1);
        mfma_q<1, 1>(acc, aF, bF);
        __builtin_amdgcn_s_setprio(0);
        BARX();
    }

    const size_t Ns = (size_t)N;
    if constexpr (OUTMODE == 2) {
        // transposed epilogue: acc -> LDS bf16 [256 n][256 m] (16B slots
        // XOR'd by n&7) with scattered scalar WRITES, then coalesced
        // vector b128 READS -> [N,M] global.
        __syncthreads();
        char* eb = smem;
#pragma unroll
        for (int g = 0; g < 8; ++g)
#pragma unroll
            for (int j = 0; j < 4; ++j) {
                const int n = wcol * 64 + j * 16 + fr;
                const float bb = bias[n0 + n];
#pragma unroll
                for (int r = 0; r < 4; ++r) {
                    float x = acc[g][j][r] + bb;
                    if (ACT) x = (x > 0.0f) ? (x + 1.0f) : __expf(x);
                    const int m = wrow * 128 + g * 16 + fq * 4 + r;
                    *(bf16*)(eb + n * 512
                        + ((((m >> 3) ^ (n & 7)) << 4) | ((m & 7) << 1)))
                        = (bf16)x;
                }
            }
        __syncthreads();
        bf16* Cp = (bf16*)Cout;
#pragma unroll
        for (int o = 0; o < 16; ++o) {
            const int n    = (tid >> 5) + o * 16;
            const int mblk = tid & 31;
            bf16x8 v = *(const bf16x8*)(eb + n * 512
                        + ((mblk ^ (n & 7)) << 4));
            *(bf16x8*)(Cp + (size_t)(n0 + n) * M + m0 + mblk * 8) = v;
        }
    } else if constexpr (OUTMODE == 3) {
        // fused attn epilogue. Wave's 64-col slice == one head (dk=64).
        __syncthreads();
        char* qb = smem + w * 16384;       // per-wave [128][64] bf16, swz
#pragma unroll
        for (int g = 0; g < 8; ++g)
#pragma unroll
            for (int j = 0; j < 4; ++j) {
                const int cq = j * 16 + fr;          // dk within head
                const float bb = bias[n0 + wcol * 64 + cq];
#pragma unroll
                for (int r = 0; r < 4; ++r) {
                    float x = acc[g][j][r] + bb;
                    x = (x > 0.0f) ? (x + 1.0f) : __expf(x);   // phi
                    const int row = g * 16 + fq * 4 + r;       // local
                    *(bf16*)(qb + row * 128
                        + ((((cq >> 3) ^ (row & 7)) << 4) | ((cq & 7) << 1)))
                        = (bf16)x;
                }
            }
        __syncthreads();

        const int hw = (n0 >> 6) + wcol;             // head 0..15
        const int bh = ((m0 >> 12) << 4) + hw;       // b*16 + h
        const bf16* kvp2 = KV2 + (size_t)bh * 6144;  // [96][64]
        bf16x8 bO[6][2];
#pragma unroll
        for (int jj = 0; jj < 6; ++jj)
#pragma unroll
            for (int ks = 0; ks < 2; ++ks)
                bO[jj][ks] = *(const bf16x8*)(kvp2
                    + (jj * 16 + fr) * 64 + ks * 32 + fq * 8);

        bf16* Cp = (bf16*)Cout;
#pragma unroll
        for (int g = 0; g < 8; ++g) {
            bf16x8 aq[2];
#pragma unroll
            for (int ks = 0; ks < 2; ++ks)
                aq[ks] = *(const bf16x8*)(qb + (g * 16 + fr) * 128
                    + ((((ks << 2) + fq) ^ l7) << 4));
            f32x4 o[6] = {};
#pragma unroll
            for (int ks = 0; ks < 2; ++ks)
#pragma unroll
                for (int jj = 0; jj < 6; ++jj)
                    o[jj] = __builtin_amdgcn_mfma_f32_16x16x32_bf16(
                        aq[ks], bO[jj][ks], o[jj], 0, 0, 0);
#pragma unroll
            for (int r = 0; r < 4; ++r) {
                const float nrm = 1.0f / (o[4][r] + o[5][r] + EPS_);
                const size_t row = (size_t)(m0 + wrow * 128 + g * 16
                                            + fq * 4 + r);
#pragma unroll
                for (int jj = 0; jj < 4; ++jj)
                    Cp[row * 1024 + n0 + wcol * 64 + jj * 16 + fr]
                        = (bf16)(o[jj][r] * nrm);
            }
        }
    } else {
        // direct epilogue: D[row=(lane>>4)*4+r][col=lane&15] per 16x16 tile
#pragma unroll
        for (int g = 0; g < 8; ++g) {
#pragma unroll
            for (int j = 0; j < 4; ++j) {
                const int col = n0 + wcol * 64 + j * 16 + fr;
                const float bb = bias[col];
                const int row0 = m0 + wrow * 128 + g * 16 + fq * 4;
#pragma unroll
                for (int r = 0; r < 4; ++r) {
                    float x = acc[g][j][r] + bb;
                    if (ACT) x = (x > 0.0f) ? (x + 1.0f) : __expf(x);
                    if (OUTMODE == 1)
                        ((float*)Cout)[(size_t)(row0 + r) * Ns + col] = x;
                    else
                        ((bf16*)Cout)[(size_t)(row0 + r) * Ns + col] = (bf16)x;
                }
            }
        }
    }
}

// ----------------------------- kv partial accumulation (MFMA over KT/VT)
// KT/VT layout [1024 = h*64+d][16384 = b*T+t]; per (bh, t-chunk of 512):
// kv[dv][dk] += sum_t VT[dv][t]*KT[dk][t]  -- a 64x64xK MFMA GEMM.
__global__ __launch_bounds__(256) void kv_partial_kernel(
    const bf16* __restrict__ KT, const bf16* __restrict__ VT,
    float* __restrict__ kv_part, float* __restrict__ ksum_part)
{
    const int bh = blockIdx.y, b = bh >> 4, h = bh & 15;
    const int tc = blockIdx.x;
    __shared__ char lds[32768];            // 2 bufs x (V 8K + K 8K)

    const int tid = threadIdx.x, wv = tid >> 6, lane = tid & 63;
    const int fr = lane & 15, fq = lane >> 4, l7 = lane & 7;

    const int r1 = wv * 8 + (lane >> 3);
    const int c1 = ((lane & 7) ^ (r1 & 7)) << 3;      // pre-swizzled t-offset
    const size_t g1 = (size_t)(h * 64 + r1) * M_ + (size_t)b * T_ + c1;
    const size_t g2 = g1 + (size_t)32 * M_;
    const int dstoff = (wv * 64 + lane) * 16;

    f32x4 acc[4] = {};
    float ksa = 0.0f;
    const int rk = tid >> 2, qk = tid & 3;

    {   // prologue: tile 0 into buf0
        const size_t mo = (size_t)tc * 512;
        async_ld16(VT + g1 + mo, lds + dstoff);
        async_ld16(VT + g2 + mo, lds + 4096 + dstoff);
        async_ld16(KT + g1 + mo, lds + 8192 + dstoff);
        async_ld16(KT + g2 + mo, lds + 12288 + dstoff);
    }
    for (int it = 0; it < 8; ++it) {
        char* cur = lds + (it & 1) * 16384;
        char* nxt = lds + ((it & 1) ^ 1) * 16384;
        if (it < 7) {
            const size_t mo = (size_t)tc * 512 + (it + 1) * 64;
            async_ld16(VT + g1 + mo, nxt + dstoff);
            async_ld16(VT + g2 + mo, nxt + 4096 + dstoff);
            async_ld16(KT + g1 + mo, nxt + 8192 + dstoff);
            async_ld16(KT + g2 + mo, nxt + 12288 + dstoff);
            asm volatile("s_waitcnt vmcnt(4)" ::: "memory");
        } else {
            asm volatile("s_waitcnt vmcnt(0)" ::: "memory");
        }
        BARX();
        const char* Vb = cur;
        const char* Kb = cur + 8192;
#pragma unroll
        for (int ks = 0; ks < 2; ++ks) {
            bf16x8 av = *(const bf16x8*)(Vb + (wv * 16 + fr) * 128
                        + ((((ks << 2) + fq) ^ l7) << 4));
#pragma unroll
            for (int j = 0; j < 4; ++j) {
                bf16x8 bk = *(const bf16x8*)(Kb + (j * 16 + fr) * 128
                            + ((((ks << 2) + fq) ^ l7) << 4));
                acc[j] = __builtin_amdgcn_mfma_f32_16x16x32_bf16(
                    av, bk, acc[j], 0, 0, 0);
            }
        }
        {   // ksum partial from the staged K tile
            bf16x8 s0 = *(const bf16x8*)(Kb + rk * 128 + (((2 * qk) ^ (rk & 7)) << 4));
            bf16x8 s1 = *(const bf16x8*)(Kb + rk * 128 + (((2 * qk + 1) ^ (rk & 7)) << 4));
#pragma unroll
            for (int e = 0; e < 8; ++e) ksa += (float)s0[e] + (float)s1[e];
        }
        BARX();
    }

    float* kvp = kv_part + ((size_t)tc * 64 + bh) * 4096;
#pragma unroll
    for (int j = 0; j < 4; ++j)
#pragma unroll
        for (int r = 0; r < 4; ++r)
            kvp[(wv * 16 + fq * 4 + r) * 64 + j * 16 + fr] = acc[j][r];

    float s = ksa;
    s += __shfl_xor(s, 1);
    s += __shfl_xor(s, 2);
    if (qk == 0) ksum_part[((size_t)tc * 64 + bh) * 64 + rk] = s;
}

// -------------------------------------------- kv reduction -> augmented kv2
// kvb2[bh][96][64]: rows 0..63 = kv[dv][dk] bf16; rows 64..79 = ksum hi
// (bf16, replicated); rows 80..95 = ksum residual lo (bf16, replicated).
__global__ __launch_bounds__(256) void kv_reduce_kernel(
    const float* __restrict__ kv_part, const float* __restrict__ ksum_part,
    bf16* __restrict__ kvb2)
{
    const int bh = blockIdx.x;
    const int tid = threadIdx.x;
    bf16* out = kvb2 + (size_t)bh * 6144;
    for (int e = tid; e < 4096; e += 256) {
        float s = 0.0f;
#pragma unroll
        for (int tc = 0; tc < 8; ++tc)
            s += kv_part[((size_t)tc * 64 + bh) * 4096 + e];
        out[e] = (bf16)s;
    }
    if (tid < 64) {
        float s = 0.0f;
#pragma unroll
        for (int tc = 0; tc < 8; ++tc)
            s += ksum_part[((size_t)tc * 64 + bh) * 64 + tid];
        const bf16 hi = (bf16)s;
        const bf16 lo = (bf16)(s - (float)hi);
#pragma unroll
        for (int i = 0; i < 16; ++i) {
            out[(64 + i) * 64 + tid] = hi;
            out[(80 + i) * 64 + tid] = lo;
        }
    }
}

// ---------------------------------------------------------------- launcher
// ws: [0,8) WT bf16 | [8,40) CVT slot (K/V bf16 act; later ATTN) |
//     [40,48) kv_part | [48,+128K) ksum_part
// d_out: [0,32) KT^T then cvt(query); [32,64) VT^T then kvb2;
//        final O-GEMM overwrites all 64 MiB with fp32 output.
extern "C" void kernel_launch(void* const* d_in, const int* in_sizes, int n_in,
                              void* d_out, int out_size, void* d_ws, size_t ws_size,
                              hipStream_t stream) {
    const float* query = (const float*)d_in[0];
    const float* key_  = (const float*)d_in[1];
    const float* value = (const float*)d_in[2];
    const float* Wq = (const float*)d_in[3];
    const float* bq = (const float*)d_in[4];
    const float* Wk = (const float*)d_in[5];
    const float* bk = (const float*)d_in[6];
    const float* Wv = (const float*)d_in[7];
    const float* bv = (const float*)d_in[8];
    const float* Wo = (const float*)d_in[9];
    const float* bo = (const float*)d_in[10];

    char* ws = (char*)d_ws;
    char* out8 = (char*)d_out;
    const size_t MB = 1024 * 1024;
    bf16* WqT = (bf16*)(ws + 0 * MB);
    bf16* WkT = (bf16*)(ws + 2 * MB);
    bf16* WvT = (bf16*)(ws + 4 * MB);
    bf16* WoT = (bf16*)(ws + 6 * MB);
    bf16* CVT = (bf16*)(ws + 8 * MB);                    // 32 MiB
    float* kv_part   = (float*)(ws + 40 * MB);           // 8 MiB
    float* ksum_part = (float*)(ws + 48 * MB);           // 128 KiB

    bf16* KTg  = (bf16*)out8;                            // d_out [0,32): K^T
    bf16* VTg  = (bf16*)(out8 + 32 * MB);                // d_out [32,64): V^T
    bf16* Qcvt = (bf16*)out8;                            // reuse after kv
    bf16* kvb2 = (bf16*)(out8 + 32 * MB);                // reuse after kv
    bf16* ATTN = CVT;                                    // reuses CVT slot

    TPtrs tp;
    tp.s[0] = Wq;  tp.s[1] = Wk;  tp.s[2] = Wv;  tp.s[3] = Wo;
    tp.d[0] = WqT; tp.d[1] = WkT; tp.d[2] = WvT; tp.d[3] = WoT;
    transpose4<<<dim3(32, 32, 4), dim3(32, 8, 1), 0, stream>>>(tp);

    const int CVT_BLOCKS = M_ * 1024 / 8 / 256;          // 8192
    const dim3 G256(4, 64);                              // N/256 x M/256

    cvt_kernel<<<CVT_BLOCKS, 256, 0, stream>>>(key_, CVT);
    gemm256_kernel<1, 2><<<G256, 512, 0, stream>>>(CVT, WkT, bk, KTg, nullptr, M_, 1024, 1024);

    cvt_kernel<<<CVT_BLOCKS, 256, 0, stream>>>(value, CVT);
    gemm256_kernel<0, 2><<<G256, 512, 0, stream>>>(CVT, WvT, bv, VTg, nullptr, M_, 1024, 1024);

    kv_partial_kernel<<<dim3(8, 64), 256, 0, stream>>>(KTg, VTg, kv_part, ksum_part);
    kv_reduce_kernel<<<dim3(64), 256, 0, stream>>>(kv_part, ksum_part, kvb2);

    cvt_kernel<<<CVT_BLOCKS, 256, 0, stream>>>(query, Qcvt);
    gemm256_kernel<1, 3><<<G256, 512, 0, stream>>>(Qcvt, WqT, bq, ATTN, kvb2, M_, 1024, 1024);

    gemm256_kernel<0, 1><<<G256, 512, 0, stream>>>(ATTN, WoT, bo, (float*)d_out, nullptr, M_, 1024, 1024);
}